// Round 15
// baseline (341.887 us; speedup 1.0000x reference)
//
#include <hip/hip_runtime.h>

#define BATCH   8
#define NNODE   2048
#define CH      256
#define NEDGE   32768
#define NLAYER  3
#define MROWS   (NNODE*BATCH)      // 16384 rows (n-major: row = n*8 + b)
#define KCAT    (3*CH)             // 768
#define NTOT    (MROWS*CH)         // 4,194,304 elements of h

#define POISON  0xAAAAAAAAu        // harness re-poisons d_ws to 0xAA bytes pre-launch

typedef _Float16 half8 __attribute__((ext_vector_type(8)));
typedef _Float16 half4 __attribute__((ext_vector_type(4)));
typedef float    f32x4 __attribute__((ext_vector_type(4)));

// ---------------- workspace layout (bytes) ----------------
// h lives ONLY in f16: Acat[:,0:256) is the current h; Hf is the mid-layer h.
// Acat cols: [0:256)=h f16, [256:512)=P1=prop(h), [512:768)=P2=prop(P1)
#define OFF_ACAT   ((size_t)0)            // f16 [MROWS][768]         25,165,824
#define OFF_HF     ((size_t)25165824)     // f16 Hf [MROWS][256]       8,388,608
#define OFF_WT     ((size_t)33554432)     // f16 Wt [3][CH][KCAT]      1,179,648
#define OFF_MT     ((size_t)34734080)     // f16 Mt [3][CH][CH]          393,216
#define OFF_PARTA  ((size_t)35127296)     // float2[512]                   4,096
#define OFF_PARTB  ((size_t)35135488)     // float2[512]                   4,096
#define OFF_CS     ((size_t)35143680)     // f32 cs[3][3][256]             9,216
#define OFF_CSM    ((size_t)35152896)     // f32 csM[3][256]               3,072
#define OFF_DEG    ((size_t)35155968)     // f32 deg[3][NNODE]            24,576
#define OFF_CNT    ((size_t)35180544)     // u32 count[3][NNODE]          24,576
#define OFF_ELIST  ((size_t)35205120)     // u32 elist[3][NNODE][64]   1,572,864
#define OFF_R1     ((size_t)36777984)     // f32 r1[3][NNODE]             24,576
#define OFF_R2     ((size_t)36802560)     // f32 r2[3][NNODE]             24,576

#define NPART 512

__device__ __forceinline__ void async_lds16(const void* g, void* l) {
  __builtin_amdgcn_global_load_lds((const __attribute__((address_space(1))) void*)g,
                                   (__attribute__((address_space(3))) void*)l, 16, 0, 0);
}

// ---- init (ONE kernel, 1101 blocks; scatter needs NO pre-zeroed state thanks to
//      the known 0xAA poison base of cnt/deg):
//  [0,512)     transpose x -> Acat0 f16 + LN0 stats (512 partials)
//  [512,896)   edge scatter: deg += w on poison base (-3e-13, negligible);
//              slot = atomicAdd(cnt)-POISON; elist
//  [896,1088)  weight fold+transpose tiles (f16 Wt/Mt)
//  [1088,1100) folded colsums from fp32 weights (coalesced rows)
//  [1100]      zero out ----
__global__ __launch_bounds__(256) void k_init(const float* __restrict__ x,
                                              _Float16* __restrict__ Acat,
                                              float2* __restrict__ part,
                                              const float* __restrict__ cheb_w,
                                              const float* __restrict__ mlp_w,
                                              const float* __restrict__ ew,
                                              const int* __restrict__ ei,
                                              _Float16* __restrict__ Wt,
                                              _Float16* __restrict__ Mt,
                                              float* __restrict__ deg,
                                              unsigned int* __restrict__ cnt,
                                              unsigned int* __restrict__ elist,
                                              float* __restrict__ cs,
                                              float* __restrict__ csM,
                                              float* __restrict__ out_zero) {
  __shared__ float rs[512];
  __shared__ _Float16 lt[64][72];
  const int blk = blockIdx.x, t = threadIdx.x;
  if (blk < 512) {
    int tid = blk*256 + t;
    float s = 0.f, s2 = 0.f;
    for (int i = tid; i < NTOT/4; i += 512*256) {
      int c4 = i & 63, b = (i >> 6) & 7, n = i >> 9;
      float4 v = ((const float4*)x)[((b*NNODE + n) << 6) + c4];
      half4 o; o[0]=(_Float16)v.x; o[1]=(_Float16)v.y; o[2]=(_Float16)v.z; o[3]=(_Float16)v.w;
      *(half4*)&Acat[(size_t)(i >> 6)*KCAT + c4*4] = o;
      s  += v.x + v.y + v.z + v.w;
      s2 += v.x*v.x + v.y*v.y + v.z*v.z + v.w*v.w;
    }
    rs[t] = s; rs[256+t] = s2; __syncthreads();
    for (int o = 128; o > 0; o >>= 1) {
      if (t < o) { rs[t] += rs[t+o]; rs[256+t] += rs[256+t+o]; }
      __syncthreads();
    }
    if (t == 0) part[blk] = make_float2(rs[0], rs[256]);
  } else if (blk < 896) {
    int i = (blk - 512)*256 + t;      // 0 .. 98303 = NLAYER*NEDGE-1
    int l = i / NEDGE, e = i % NEDGE;
    const int* rows = ei + l*2*NEDGE;
    const int* cols = rows + NEDGE;
    int r = rows[e], c = cols[e];
    float w = (r == c) ? 0.f : ew[i];
    atomicAdd(&deg[l*NNODE + r], w);  // base = poison float -3.03e-13: negligible
    unsigned int slot = atomicAdd(&cnt[l*NNODE + c], 1u) - POISON;
    if (slot < 64u) elist[((size_t)(l*NNODE + c) << 6) + slot] = (unsigned int)e;
  } else if (blk < 1088) {
    const int tile = blk - 896;
    const int rr = t >> 4, c4 = t & 15;
    if (tile < 144) {
      const int l = tile / 48, rem = tile % 48;
      const int kk = rem / 16, q = rem % 16, ci = q >> 2, ni = q & 3;
      const float4* W  = (const float4*)cheb_w + ((size_t)((l*3 + kk)*CH + ci*64))*64 + ni*16;
      const float4* W2 = (const float4*)cheb_w + ((size_t)((l*3 + 2 )*CH + ci*64))*64 + ni*16;
      #pragma unroll
      for (int p = 0; p < 4; ++p) {
        const int r = p*16 + rr;
        float4 v = W[(size_t)r*64 + c4];
        if (kk == 0) {
          float4 v2 = W2[(size_t)r*64 + c4];
          v.x -= v2.x; v.y -= v2.y; v.z -= v2.z; v.w -= v2.w;
        } else if (kk == 2) {
          v.x *= 2.f; v.y *= 2.f; v.z *= 2.f; v.w *= 2.f;
        }
        lt[c4*4+0][r] = (_Float16)v.x; lt[c4*4+1][r] = (_Float16)v.y;
        lt[c4*4+2][r] = (_Float16)v.z; lt[c4*4+3][r] = (_Float16)v.w;
      }
      __syncthreads();
      const int nr = t >> 2, ch2 = t & 3;
      #pragma unroll
      for (int pp = 0; pp < 2; ++pp) {
        const int ch = ch2 + pp*4;
        half8 v = *(const half8*)&lt[nr][ch*8];
        *(half8*)&Wt[((size_t)(l*CH + ni*64 + nr))*KCAT + kk*256 + ci*64 + ch*8] = v;
      }
    } else {
      const int m = tile - 144;
      const int l = m / 16, q = m % 16, ci = q >> 2, ni = q & 3;
      const float4* W = (const float4*)mlp_w + ((size_t)(l*CH + ci*64))*64 + ni*16;
      #pragma unroll
      for (int p = 0; p < 4; ++p) {
        const int r = p*16 + rr;
        float4 v = W[(size_t)r*64 + c4];
        lt[c4*4+0][r] = (_Float16)v.x; lt[c4*4+1][r] = (_Float16)v.y;
        lt[c4*4+2][r] = (_Float16)v.z; lt[c4*4+3][r] = (_Float16)v.w;
      }
      __syncthreads();
      const int nr = t >> 2, ch2 = t & 3;
      #pragma unroll
      for (int pp = 0; pp < 2; ++pp) {
        const int ch = ch2 + pp*4;
        half8 v = *(const half8*)&lt[nr][ch*8];
        *(half8*)&Mt[((size_t)(l*CH + ni*64 + nr))*CH + ci*64 + ch*8] = v;
      }
    }
  } else if (blk < 1100) {
    // folded colsums from fp32 weights; thread t = col n, rows contiguous (coalesced)
    const int idx = blk - 1088, n = t;
    if (idx < 9) {
      const int l = idx / 3, kk = idx % 3;
      const float* W0 = cheb_w + (size_t)((l*3 + kk)*CH)*CH + n;
      const float* W2 = cheb_w + (size_t)((l*3 + 2 )*CH)*CH + n;
      float s = 0.f;
      for (int cin = 0; cin < CH; ++cin) {
        float wv = W0[(size_t)cin*CH];
        if (kk == 0)      wv -= W2[(size_t)cin*CH];
        else if (kk == 2) wv *= 2.f;
        s += wv;
      }
      cs[(l*3 + kk)*CH + n] = s;
    } else {
      const int l = idx - 9;
      const float* W = mlp_w + (size_t)l*CH*CH + n;
      float s = 0.f;
      for (int k2 = 0; k2 < CH; ++k2) s += W[(size_t)k2*CH];
      csM[l*CH + n] = s;
    }
  } else {
    for (int i = t; i < BATCH*CH; i += 256) out_zero[i] = 0.f;
  }
}

// ---- sparse prop: wave = one dst x 2 batch slices (32 lanes x half8 each).
//      2048 blocks; bpair = blk&3 -> one bpair class per XCD (round-robin mod 8),
//      keeping each XCD's gather slice (2 MB) L2-resident. norm on the fly.
//      cnt carries the poison base. RMODE=1 (bp==0): r1[dst]=sum(nm);
//      RMODE=2: r2[dst]=sum(nm*r1[src]). ----
template<int SRC_OFF, int DST_OFF, int RMODE>
__global__ __launch_bounds__(256) void k_prop(_Float16* __restrict__ Acat,
                                              const int* __restrict__ rows,
                                              const float* __restrict__ ew_l,
                                              const float* __restrict__ deg_l,
                                              const unsigned int* __restrict__ count,
                                              const unsigned int* __restrict__ el,
                                              float* __restrict__ r1_l,
                                              float* __restrict__ r2_l) {
  const int blk = blockIdx.x, t = threadIdx.x;
  const int bp = blk & 3, dgrp = blk >> 2;
  const int w = t >> 6, lane = t & 63;
  const int dst = dgrp*4 + w;
  const int b = bp*2 + (lane >> 5), l32 = lane & 31;
  unsigned int c = count[dst] - POISON; if (c > 64u) c = 64u;
  const float dc = deg_l[dst];
  const float ic = dc > 0.f ? rsqrtf(fmaxf(dc, 1e-12f)) : 0.f;
  int srcv = 0; float nmv = 0.f;
  if (lane < (int)c) {
    unsigned int e = el[(size_t)dst*64 + lane];
    srcv = rows[e];
    float wv = (srcv == dst) ? 0.f : ew_l[e];
    float dr = deg_l[srcv];
    float ir = dr > 0.f ? rsqrtf(fmaxf(dr, 1e-12f)) : 0.f;
    nmv = -(ir * wv * ic);
  }
  if (RMODE && bp == 0) {
    float rv = nmv;
    if (RMODE == 2) rv = (lane < (int)c) ? nmv * r1_l[srcv] : 0.f;
    #pragma unroll
    for (int o = 32; o > 0; o >>= 1) rv += __shfl_xor(rv, o);
    if (lane == 0) { if (RMODE == 1) r1_l[dst] = rv; else r2_l[dst] = rv; }
  }
  float a0=0.f,a1=0.f,a2=0.f,a3=0.f,a4=0.f,a5=0.f,a6=0.f,a7=0.f;
  const _Float16* base = Acat + SRC_OFF + (size_t)b*KCAT + l32*8;
  #define PROP_STEP(i)                                                            \
    {                                                                             \
      int   src = __builtin_amdgcn_readlane(srcv, (i));                           \
      int   nbi = __builtin_amdgcn_readlane(__builtin_bit_cast(int, nmv), (i));   \
      float nm  = __builtin_bit_cast(float, nbi);                                 \
      half8 v = *(const half8*)&base[(size_t)src*8*KCAT];                         \
      a0 += nm*(float)v[0]; a1 += nm*(float)v[1];                                 \
      a2 += nm*(float)v[2]; a3 += nm*(float)v[3];                                 \
      a4 += nm*(float)v[4]; a5 += nm*(float)v[5];                                 \
      a6 += nm*(float)v[6]; a7 += nm*(float)v[7];                                 \
    }
  unsigned int i = 0;
  for (; i + 4 <= c; i += 4) { PROP_STEP(i) PROP_STEP(i+1) PROP_STEP(i+2) PROP_STEP(i+3) }
  for (; i < c; ++i) { PROP_STEP(i) }
  #undef PROP_STEP
  half8 o;
  o[0]=(_Float16)a0; o[1]=(_Float16)a1; o[2]=(_Float16)a2; o[3]=(_Float16)a3;
  o[4]=(_Float16)a4; o[5]=(_Float16)a5; o[6]=(_Float16)a6; o[7]=(_Float16)a7;
  *(half8*)&Acat[(size_t)(dst*8 + b)*KCAT + DST_OFF + l32*8] = o;
}

// ---- MFMA GEMM 128x64 tile, BK=128 (half the barriers of BK=64), mod-16
//      XOR-swizzled LDS, LN folded into epilogue. K = KSTEPS*128. f16 state. ----
template<int KSTEPS, int DO_GELU>
__global__ __launch_bounds__(256) void k_gemm(const _Float16* __restrict__ A, int lda,
                                              const _Float16* __restrict__ Bt, int ldb,
                                              const float* __restrict__ bias,
                                              const float* __restrict__ cs,
                                              const float* __restrict__ r1,
                                              const float* __restrict__ r2,
                                              const float2* __restrict__ part_in,
                                              float2* __restrict__ part_out,
                                              const _Float16* __restrict__ R, int ldr,
                                              _Float16* __restrict__ O, int ldo) {
  __shared__ _Float16 Als[128*128];  // 32 KB
  __shared__ _Float16 Bls[64*128];   // 16 KB
  __shared__ float red[512];
  __shared__ float mv[2];
  const int bm = blockIdx.x, bn = blockIdx.y;
  const int t = threadIdx.x;
  const int w = t >> 6, lane = t & 63;
  const int quad = lane >> 4, l16 = lane & 15;
  const int rw = w & 1, cw = w >> 1;   // wave tile: 64 rows x 32 cols

  // ---- reduce stats partials of input h -> (mean, istd) ----
  {
    float s = 0.f, s2 = 0.f;
    for (int i = t; i < NPART; i += 256) { float2 p = part_in[i]; s += p.x; s2 += p.y; }
    red[t] = s; red[256+t] = s2; __syncthreads();
    for (int o = 128; o > 0; o >>= 1) {
      if (t < o) { red[t] += red[t+o]; red[256+t] += red[256+t+o]; }
      __syncthreads();
    }
    if (t == 0) {
      float mean = red[0] * (1.f/(float)NTOT);
      float var  = red[256] * (1.f/(float)NTOT) - mean*mean;
      mv[0] = mean; mv[1] = rsqrtf(var + 1e-5f);
    }
    __syncthreads();
  }
  const float mean = mv[0], istd = mv[1];

  f32x4 acc[4][2];
  #pragma unroll
  for (int i = 0; i < 4; ++i)
    #pragma unroll
    for (int j = 0; j < 2; ++j) acc[i][j] = (f32x4){0.f,0.f,0.f,0.f};

  // staging: A = 2048 16B chunks (8/thread), B = 1024 (4/thread).
  // chunk c: row r = c>>4, phys slot c&15 holds global kseg (c&15)^(r&15).
  const _Float16* ga[8];
  const _Float16* gb[4];
  #pragma unroll
  for (int j = 0; j < 8; ++j) {
    const int c = j*256 + t, r = c >> 4, s = (c & 15) ^ (r & 15);
    ga[j] = A + (size_t)(bm*128 + r)*lda + s*8;
  }
  #pragma unroll
  for (int j = 0; j < 4; ++j) {
    const int c = j*256 + t, r = c >> 4, s = (c & 15) ^ (r & 15);
    gb[j] = Bt + (size_t)(bn*64 + r)*ldb + s*8;
  }

  for (int ks = 0; ks < KSTEPS; ++ks) {
    #pragma unroll
    for (int j = 0; j < 8; ++j) async_lds16(ga[j], &Als[j*2048 + w*512]);
    #pragma unroll
    for (int j = 0; j < 4; ++j) async_lds16(gb[j], &Bls[j*2048 + w*512]);
    #pragma unroll
    for (int j = 0; j < 8; ++j) ga[j] += 128;
    #pragma unroll
    for (int j = 0; j < 4; ++j) gb[j] += 128;
    __syncthreads();
    #pragma unroll
    for (int kh = 0; kh < 4; ++kh) {   // global kseg = kh*4 + quad (0..15)
      const int q = kh*4 + quad;
      half8 bf[2];
      #pragma unroll
      for (int j = 0; j < 2; ++j) {
        const int rb = cw*32 + j*16 + l16;
        bf[j] = *(const half8*)&Bls[rb*128 + (q ^ (rb & 15))*8];
      }
      #pragma unroll
      for (int i = 0; i < 4; ++i) {
        const int ra = rw*64 + i*16 + l16;
        half8 af = *(const half8*)&Als[ra*128 + (q ^ (ra & 15))*8];
        acc[i][0] = __builtin_amdgcn_mfma_f32_16x16x32_f16(af, bf[0], acc[i][0], 0, 0, 0);
        acc[i][1] = __builtin_amdgcn_mfma_f32_16x16x32_f16(af, bf[1], acc[i][1], 0, 0, 0);
      }
    }
    __syncthreads();
  }

  float s = 0.f, s2 = 0.f;
  const int gm0 = bm*128 + rw*64, gn0 = bn*64 + cw*32;
  const float mi = -mean * istd;
  #pragma unroll
  for (int i = 0; i < 4; ++i) {
    #pragma unroll
    for (int j = 0; j < 2; ++j) {
      f32x4 a = acc[i][j];
      const int col = gn0 + j*16 + l16;
      const float bv = bias[col];
      const float c0v = cs[col];
      float c1v = 0.f, c2v = 0.f;
      if (!DO_GELU) { c1v = cs[256 + col]; c2v = cs[512 + col]; }
      #pragma unroll
      for (int r = 0; r < 4; ++r) {
        const int row = gm0 + i*16 + quad*4 + r;   // C/D: col=lane&15, row=quad*4+reg
        float v;
        if (DO_GELU) {
          v = istd*a[r] + mi*c0v + bv;
          v = 0.5f*v*(1.f + erff(v*0.70710678118654752f));
        } else {
          const int node = row >> 3;
          v = istd*a[r] + mi*(c0v + r1[node]*c1v + r2[node]*c2v) + bv;
        }
        float hv = (float)R[(size_t)row*ldr + col] + v;
        O[(size_t)row*ldo + col] = (_Float16)hv;
        s += hv; s2 += hv*hv;
      }
    }
  }
  red[t] = s; red[256+t] = s2; __syncthreads();
  for (int o = 128; o > 0; o >>= 1) {
    if (t < o) { red[t] += red[t+o]; red[256+t] += red[256+t+o]; }
    __syncthreads();
  }
  if (t == 0) part_out[blockIdx.y*gridDim.x + blockIdx.x] = make_float2(red[0], red[256]);
}

// ---- final mean over N: 64 blocks, one atomic per thread into pre-zeroed out ----
__global__ __launch_bounds__(256) void k_mean(const _Float16* __restrict__ Acat,
                                              float* __restrict__ out) {
  int b = blockIdx.x & 7, chunk = blockIdx.x >> 3;   // 8 chunks x 256 nodes
  int c = threadIdx.x;
  float s = 0.f;
  for (int k = 0; k < 256; ++k) {
    int n = chunk*256 + k;
    s += (float)Acat[(size_t)(n*8 + b)*KCAT + c];
  }
  atomicAdd(&out[(b << 8) + c], s * (1.f/(float)NNODE));
}

extern "C" void kernel_launch(void* const* d_in, const int* in_sizes, int n_in,
                              void* d_out, int out_size, void* d_ws, size_t ws_size,
                              hipStream_t stream) {
  const float* x      = (const float*)d_in[0];   // node_feature [8,2048,256]
  const float* ew     = (const float*)d_in[1];   // edge_weight [3,32768]
  const float* cheb_w = (const float*)d_in[2];   // [3,3,256,256]
  const float* cheb_b = (const float*)d_in[3];   // [3,256]
  const float* mlp_w  = (const float*)d_in[4];   // [3,256,256]
  const float* mlp_b  = (const float*)d_in[5];   // [3,256]
  const int*   ei     = (const int*)d_in[6];     // [3,2,32768]
  float* out = (float*)d_out;

  char* ws = (char*)d_ws;
  _Float16*     Acat  = (_Float16*)(ws + OFF_ACAT);
  _Float16*     Hf    = (_Float16*)(ws + OFF_HF);
  _Float16*     Wt    = (_Float16*)(ws + OFF_WT);
  _Float16*     Mt    = (_Float16*)(ws + OFF_MT);
  float2*       partA = (float2*)(ws + OFF_PARTA);
  float2*       partB = (float2*)(ws + OFF_PARTB);
  float*        cs    = (float*)(ws + OFF_CS);
  float*        csM   = (float*)(ws + OFF_CSM);
  float*        deg   = (float*)(ws + OFF_DEG);
  unsigned int* cnt   = (unsigned int*)(ws + OFF_CNT);
  unsigned int* elist = (unsigned int*)(ws + OFF_ELIST);
  float*        r1    = (float*)(ws + OFF_R1);
  float*        r2    = (float*)(ws + OFF_R2);

  k_init<<<1101, 256, 0, stream>>>(x, Acat, partA, cheb_w, mlp_w, ew, ei,
                                   Wt, Mt, deg, cnt, elist, cs, csM, out);

  for (int l = 0; l < NLAYER; ++l) {
    const int* rows_l = ei + l*2*NEDGE;
    const float* ew_l = ew + l*NEDGE;
    const float* deg_l = deg + l*NNODE;
    const unsigned int* cnt_l = cnt + l*NNODE;
    const unsigned int* el_l  = elist + (size_t)l*NNODE*64;
    float* r1_l = r1 + l*NNODE;
    float* r2_l = r2 + l*NNODE;

    // P1 = prop(h) -> Acat[:,256:512); bp==0 blocks also emit r1 = prop(ones)
    k_prop<0, 256, 1><<<2048, 256, 0, stream>>>(
        Acat, rows_l, ew_l, deg_l, cnt_l, el_l, r1_l, r2_l);
    // P2 = prop(P1) -> Acat[:,512:768); bp==0 blocks also emit r2 = prop(r1)
    k_prop<256, 512, 2><<<2048, 256, 0, stream>>>(
        Acat, rows_l, ew_l, deg_l, cnt_l, el_l, r1_l, r2_l);
    // Hf = h + LN-corrected [h|P1|P2]@W' + cheb_b ; stats -> partB
    k_gemm<6, 0><<<dim3(128, 4), 256, 0, stream>>>(
        Acat, KCAT, Wt + (size_t)l*CH*KCAT, KCAT, cheb_b + l*CH,
        cs + l*3*CH, r1_l, r2_l, partA, partB,
        Acat, KCAT, Hf, CH);
    // h(new, ->Acat0) = Hf + gelu(LN-corrected Hf@M + mlp_b) ; stats -> partA
    k_gemm<2, 1><<<dim3(128, 4), 256, 0, stream>>>(
        Hf, CH, Mt + (size_t)l*CH*CH, CH, mlp_b + l*CH,
        csM + l*CH, r1_l, r2_l, partB, partA,
        Hf, CH, Acat, KCAT);
  }

  k_mean<<<64, 256, 0, stream>>>(Acat, out);
}

// Round 16
// 255.527 us; speedup vs baseline: 1.3380x; 1.3380x over previous
//
#include <hip/hip_runtime.h>

#define BATCH   8
#define NNODE   2048
#define CH      256
#define NEDGE   32768
#define NLAYER  3
#define MROWS   (NNODE*BATCH)      // 16384 rows (n-major: row = n*8 + b)
#define KCAT    (3*CH)             // 768
#define NTOT    (MROWS*CH)         // 4,194,304 elements of h

typedef _Float16 half8 __attribute__((ext_vector_type(8)));
typedef _Float16 half4 __attribute__((ext_vector_type(4)));
typedef float    f32x4 __attribute__((ext_vector_type(4)));

// ---------------- workspace layout (bytes) ----------------
// h lives ONLY in f16: Acat[:,0:256) is the current h; Hf is the mid-layer h.
// Acat cols: [0:256)=h f16, [256:512)=P1=prop(h), [512:768)=P2=prop(P1)
#define OFF_ACAT   ((size_t)0)            // f16 [MROWS][768]         25,165,824
#define OFF_HF     ((size_t)25165824)     // f16 Hf [MROWS][256]       8,388,608
#define OFF_WT     ((size_t)33554432)     // f16 Wt [3][CH][KCAT]      1,179,648
#define OFF_MT     ((size_t)34734080)     // f16 Mt [3][CH][CH]          393,216
#define OFF_PARTA  ((size_t)35127296)     // float2[512]                   4,096
#define OFF_PARTB  ((size_t)35135488)     // float2[512]                   4,096
#define OFF_CS     ((size_t)35143680)     // f32 cs[3][3][256]             9,216
#define OFF_CSM    ((size_t)35152896)     // f32 csM[3][256]               3,072
#define OFF_DEG    ((size_t)35155968)     // f32 deg[3][NNODE]            24,576
#define OFF_CNT    ((size_t)35180544)     // u32 count[3][NNODE]          24,576
#define OFF_ELIST  ((size_t)35205120)     // u32 elist[3][NNODE][64]   1,572,864
#define OFF_R1     ((size_t)36777984)     // f32 r1[3][NNODE]             24,576
#define OFF_R2     ((size_t)36802560)     // f32 r2[3][NNODE]             24,576

#define NPART 512

__device__ __forceinline__ void async_lds16(const void* g, void* l) {
  __builtin_amdgcn_global_load_lds((const __attribute__((address_space(1))) void*)g,
                                   (__attribute__((address_space(3))) void*)l, 16, 0, 0);
}

// ---- init: blocks [0,512) transpose x -> Acat0 f16 + LN0 stats (512 partials);
//      [512,536) zero deg/cnt; [536,728) weight fold+transpose tiles ----
// NOTE (R13/R15 evidence): do NOT merge the edge scatter into this kernel —
// its atomics co-resident with the 75 MB transpose stream cost ~60-70 µs.
__global__ __launch_bounds__(256) void k_init(const float* __restrict__ x,
                                              _Float16* __restrict__ Acat,
                                              float2* __restrict__ part,
                                              const float* __restrict__ cheb_w,
                                              const float* __restrict__ mlp_w,
                                              _Float16* __restrict__ Wt,
                                              _Float16* __restrict__ Mt,
                                              float* __restrict__ deg,
                                              unsigned int* __restrict__ count) {
  __shared__ float rs[512];
  __shared__ _Float16 lt[64][72];
  const int blk = blockIdx.x, t = threadIdx.x;
  if (blk < 512) {
    int tid = blk*256 + t;
    float s = 0.f, s2 = 0.f;
    for (int i = tid; i < NTOT/4; i += 512*256) {
      int c4 = i & 63, b = (i >> 6) & 7, n = i >> 9;
      float4 v = ((const float4*)x)[((b*NNODE + n) << 6) + c4];
      half4 o; o[0]=(_Float16)v.x; o[1]=(_Float16)v.y; o[2]=(_Float16)v.z; o[3]=(_Float16)v.w;
      *(half4*)&Acat[(size_t)(i >> 6)*KCAT + c4*4] = o;
      s  += v.x + v.y + v.z + v.w;
      s2 += v.x*v.x + v.y*v.y + v.z*v.z + v.w*v.w;
    }
    rs[t] = s; rs[256+t] = s2; __syncthreads();
    for (int o = 128; o > 0; o >>= 1) {
      if (t < o) { rs[t] += rs[t+o]; rs[256+t] += rs[256+t+o]; }
      __syncthreads();
    }
    if (t == 0) part[blk] = make_float2(rs[0], rs[256]);
  } else if (blk < 536) {
    int i = (blk - 512)*256 + t;
    if (i < NLAYER*NNODE) { deg[i] = 0.f; count[i] = 0u; }
  } else {
    const int tile = blk - 536;
    const int rr = t >> 4, c4 = t & 15;
    if (tile < 144) {
      const int l = tile / 48, rem = tile % 48;
      const int kk = rem / 16, q = rem % 16, ci = q >> 2, ni = q & 3;
      const float4* W  = (const float4*)cheb_w + ((size_t)((l*3 + kk)*CH + ci*64))*64 + ni*16;
      const float4* W2 = (const float4*)cheb_w + ((size_t)((l*3 + 2 )*CH + ci*64))*64 + ni*16;
      #pragma unroll
      for (int p = 0; p < 4; ++p) {
        const int r = p*16 + rr;
        float4 v = W[(size_t)r*64 + c4];
        if (kk == 0) {
          float4 v2 = W2[(size_t)r*64 + c4];
          v.x -= v2.x; v.y -= v2.y; v.z -= v2.z; v.w -= v2.w;
        } else if (kk == 2) {
          v.x *= 2.f; v.y *= 2.f; v.z *= 2.f; v.w *= 2.f;
        }
        lt[c4*4+0][r] = (_Float16)v.x; lt[c4*4+1][r] = (_Float16)v.y;
        lt[c4*4+2][r] = (_Float16)v.z; lt[c4*4+3][r] = (_Float16)v.w;
      }
      __syncthreads();
      const int nr = t >> 2, ch2 = t & 3;
      #pragma unroll
      for (int pp = 0; pp < 2; ++pp) {
        const int ch = ch2 + pp*4;
        half8 v = *(const half8*)&lt[nr][ch*8];
        *(half8*)&Wt[((size_t)(l*CH + ni*64 + nr))*KCAT + kk*256 + ci*64 + ch*8] = v;
      }
    } else {
      const int m = tile - 144;
      const int l = m / 16, q = m % 16, ci = q >> 2, ni = q & 3;
      const float4* W = (const float4*)mlp_w + ((size_t)(l*CH + ci*64))*64 + ni*16;
      #pragma unroll
      for (int p = 0; p < 4; ++p) {
        const int r = p*16 + rr;
        float4 v = W[(size_t)r*64 + c4];
        lt[c4*4+0][r] = (_Float16)v.x; lt[c4*4+1][r] = (_Float16)v.y;
        lt[c4*4+2][r] = (_Float16)v.z; lt[c4*4+3][r] = (_Float16)v.w;
      }
      __syncthreads();
      const int nr = t >> 2, ch2 = t & 3;
      #pragma unroll
      for (int pp = 0; pp < 2; ++pp) {
        const int ch = ch2 + pp*4;
        half8 v = *(const half8*)&lt[nr][ch*8];
        *(half8*)&Mt[((size_t)(l*CH + ni*64 + nr))*CH + ci*64 + ch*8] = v;
      }
    }
  }
}

// ---- scatter: blocks [0,384) deg/cnt/elist; [384,393) cs; [393,396) csM; [396] zero out ----
__global__ __launch_bounds__(256) void k_edge_scatter(const int* __restrict__ ei,
                                                      const float* __restrict__ ew,
                                                      float* deg, unsigned int* count,
                                                      unsigned int* elist,
                                                      const _Float16* __restrict__ Wt,
                                                      const _Float16* __restrict__ Mt,
                                                      float* __restrict__ cs,
                                                      float* __restrict__ csM,
                                                      float* __restrict__ out_zero) {
  const int blk = blockIdx.x, t = threadIdx.x;
  if (blk < 384) {
    int i = blk*256 + t;
    int l = i / NEDGE, e = i % NEDGE;
    const int* rows = ei + l*2*NEDGE;
    const int* cols = rows + NEDGE;
    int r = rows[e], c = cols[e];
    float w = (r == c) ? 0.f : ew[i];
    atomicAdd(&deg[l*NNODE + r], w);
    unsigned int slot = atomicAdd(&count[l*NNODE + c], 1u);
    if (slot < 64u) elist[(size_t)(l*NNODE + c)*64 + slot] = (unsigned int)e;
  } else if (blk < 393) {
    int idx = blk - 384, l = idx / 3, kk = idx % 3, n = t;
    const half8* row = (const half8*)&Wt[((size_t)(l*CH + n))*KCAT + kk*256];
    float s = 0.f;
    #pragma unroll 4
    for (int j = 0; j < 32; ++j) {
      half8 v = row[j];
      s += (float)v[0]+(float)v[1]+(float)v[2]+(float)v[3]
         + (float)v[4]+(float)v[5]+(float)v[6]+(float)v[7];
    }
    cs[(l*3 + kk)*CH + n] = s;
  } else if (blk < 396) {
    int l = blk - 393, n = t;
    const half8* row = (const half8*)&Mt[((size_t)(l*CH + n))*CH];
    float s = 0.f;
    #pragma unroll 4
    for (int j = 0; j < 32; ++j) {
      half8 v = row[j];
      s += (float)v[0]+(float)v[1]+(float)v[2]+(float)v[3]
         + (float)v[4]+(float)v[5]+(float)v[6]+(float)v[7];
    }
    csM[l*CH + n] = s;
  } else {
    for (int i = t; i < BATCH*CH; i += 256) out_zero[i] = 0.f;
  }
}

// ---- sparse prop: wave = one dst x 2 batch slices (32 lanes x half8 each).
//      2048 blocks; bpair = blk&3 -> one bpair class per XCD (round-robin mod 8),
//      keeping each XCD's gather slice (2 MB) L2-resident. norm on the fly.
//      RMODE=1 (bpair==0): r1[dst]=sum(nm); RMODE=2: r2[dst]=sum(nm*r1[src]). ----
template<int SRC_OFF, int DST_OFF, int RMODE>
__global__ __launch_bounds__(256) void k_prop(_Float16* __restrict__ Acat,
                                              const int* __restrict__ rows,
                                              const float* __restrict__ ew_l,
                                              const float* __restrict__ deg_l,
                                              const unsigned int* __restrict__ count,
                                              const unsigned int* __restrict__ el,
                                              float* __restrict__ r1_l,
                                              float* __restrict__ r2_l) {
  const int blk = blockIdx.x, t = threadIdx.x;
  const int bp = blk & 3, dgrp = blk >> 2;
  const int w = t >> 6, lane = t & 63;
  const int dst = dgrp*4 + w;
  const int b = bp*2 + (lane >> 5), l32 = lane & 31;
  unsigned int c = count[dst]; if (c > 64u) c = 64u;
  const float dc = deg_l[dst];
  const float ic = dc > 0.f ? rsqrtf(fmaxf(dc, 1e-12f)) : 0.f;
  int srcv = 0; float nmv = 0.f;
  if (lane < (int)c) {
    unsigned int e = el[(size_t)dst*64 + lane];
    srcv = rows[e];
    float wv = (srcv == dst) ? 0.f : ew_l[e];
    float dr = deg_l[srcv];
    float ir = dr > 0.f ? rsqrtf(fmaxf(dr, 1e-12f)) : 0.f;
    nmv = -(ir * wv * ic);
  }
  if (RMODE && bp == 0) {
    float rv = nmv;
    if (RMODE == 2) rv = (lane < (int)c) ? nmv * r1_l[srcv] : 0.f;
    #pragma unroll
    for (int o = 32; o > 0; o >>= 1) rv += __shfl_xor(rv, o);
    if (lane == 0) { if (RMODE == 1) r1_l[dst] = rv; else r2_l[dst] = rv; }
  }
  float a0=0.f,a1=0.f,a2=0.f,a3=0.f,a4=0.f,a5=0.f,a6=0.f,a7=0.f;
  const _Float16* base = Acat + SRC_OFF + (size_t)b*KCAT + l32*8;
  #define PROP_STEP(i)                                                            \
    {                                                                             \
      int   src = __builtin_amdgcn_readlane(srcv, (i));                           \
      int   nbi = __builtin_amdgcn_readlane(__builtin_bit_cast(int, nmv), (i));   \
      float nm  = __builtin_bit_cast(float, nbi);                                 \
      half8 v = *(const half8*)&base[(size_t)src*8*KCAT];                         \
      a0 += nm*(float)v[0]; a1 += nm*(float)v[1];                                 \
      a2 += nm*(float)v[2]; a3 += nm*(float)v[3];                                 \
      a4 += nm*(float)v[4]; a5 += nm*(float)v[5];                                 \
      a6 += nm*(float)v[6]; a7 += nm*(float)v[7];                                 \
    }
  unsigned int i = 0;
  for (; i + 4 <= c; i += 4) { PROP_STEP(i) PROP_STEP(i+1) PROP_STEP(i+2) PROP_STEP(i+3) }
  for (; i < c; ++i) { PROP_STEP(i) }
  #undef PROP_STEP
  half8 o;
  o[0]=(_Float16)a0; o[1]=(_Float16)a1; o[2]=(_Float16)a2; o[3]=(_Float16)a3;
  o[4]=(_Float16)a4; o[5]=(_Float16)a5; o[6]=(_Float16)a6; o[7]=(_Float16)a7;
  *(half8*)&Acat[(size_t)(dst*8 + b)*KCAT + DST_OFF + l32*8] = o;
}

// ---- MFMA GEMM 128x64 tile, BK=128 (half the barriers of BK=64), mod-16
//      XOR-swizzled LDS, LN folded into epilogue. K = KSTEPS*128. f16 state. ----
template<int KSTEPS, int DO_GELU>
__global__ __launch_bounds__(256) void k_gemm(const _Float16* __restrict__ A, int lda,
                                              const _Float16* __restrict__ Bt, int ldb,
                                              const float* __restrict__ bias,
                                              const float* __restrict__ cs,
                                              const float* __restrict__ r1,
                                              const float* __restrict__ r2,
                                              const float2* __restrict__ part_in,
                                              float2* __restrict__ part_out,
                                              const _Float16* __restrict__ R, int ldr,
                                              _Float16* __restrict__ O, int ldo) {
  __shared__ _Float16 Als[128*128];  // 32 KB
  __shared__ _Float16 Bls[64*128];   // 16 KB
  __shared__ float red[512];
  __shared__ float mv[2];
  const int bm = blockIdx.x, bn = blockIdx.y;
  const int t = threadIdx.x;
  const int w = t >> 6, lane = t & 63;
  const int quad = lane >> 4, l16 = lane & 15;
  const int rw = w & 1, cw = w >> 1;   // wave tile: 64 rows x 32 cols

  // ---- reduce stats partials of input h -> (mean, istd) ----
  {
    float s = 0.f, s2 = 0.f;
    for (int i = t; i < NPART; i += 256) { float2 p = part_in[i]; s += p.x; s2 += p.y; }
    red[t] = s; red[256+t] = s2; __syncthreads();
    for (int o = 128; o > 0; o >>= 1) {
      if (t < o) { red[t] += red[t+o]; red[256+t] += red[256+t+o]; }
      __syncthreads();
    }
    if (t == 0) {
      float mean = red[0] * (1.f/(float)NTOT);
      float var  = red[256] * (1.f/(float)NTOT) - mean*mean;
      mv[0] = mean; mv[1] = rsqrtf(var + 1e-5f);
    }
    __syncthreads();
  }
  const float mean = mv[0], istd = mv[1];

  f32x4 acc[4][2];
  #pragma unroll
  for (int i = 0; i < 4; ++i)
    #pragma unroll
    for (int j = 0; j < 2; ++j) acc[i][j] = (f32x4){0.f,0.f,0.f,0.f};

  // staging: A = 2048 16B chunks (8/thread), B = 1024 (4/thread).
  // chunk c: row r = c>>4, phys slot c&15 holds global kseg (c&15)^(r&15).
  const _Float16* ga[8];
  const _Float16* gb[4];
  #pragma unroll
  for (int j = 0; j < 8; ++j) {
    const int c = j*256 + t, r = c >> 4, s = (c & 15) ^ (r & 15);
    ga[j] = A + (size_t)(bm*128 + r)*lda + s*8;
  }
  #pragma unroll
  for (int j = 0; j < 4; ++j) {
    const int c = j*256 + t, r = c >> 4, s = (c & 15) ^ (r & 15);
    gb[j] = Bt + (size_t)(bn*64 + r)*ldb + s*8;
  }

  for (int ks = 0; ks < KSTEPS; ++ks) {
    #pragma unroll
    for (int j = 0; j < 8; ++j) async_lds16(ga[j], &Als[j*2048 + w*512]);
    #pragma unroll
    for (int j = 0; j < 4; ++j) async_lds16(gb[j], &Bls[j*2048 + w*512]);
    #pragma unroll
    for (int j = 0; j < 8; ++j) ga[j] += 128;
    #pragma unroll
    for (int j = 0; j < 4; ++j) gb[j] += 128;
    __syncthreads();
    #pragma unroll
    for (int kh = 0; kh < 4; ++kh) {   // global kseg = kh*4 + quad (0..15)
      const int q = kh*4 + quad;
      half8 bf[2];
      #pragma unroll
      for (int j = 0; j < 2; ++j) {
        const int rb = cw*32 + j*16 + l16;
        bf[j] = *(const half8*)&Bls[rb*128 + (q ^ (rb & 15))*8];
      }
      #pragma unroll
      for (int i = 0; i < 4; ++i) {
        const int ra = rw*64 + i*16 + l16;
        half8 af = *(const half8*)&Als[ra*128 + (q ^ (ra & 15))*8];
        acc[i][0] = __builtin_amdgcn_mfma_f32_16x16x32_f16(af, bf[0], acc[i][0], 0, 0, 0);
        acc[i][1] = __builtin_amdgcn_mfma_f32_16x16x32_f16(af, bf[1], acc[i][1], 0, 0, 0);
      }
    }
    __syncthreads();
  }

  float s = 0.f, s2 = 0.f;
  const int gm0 = bm*128 + rw*64, gn0 = bn*64 + cw*32;
  const float mi = -mean * istd;
  #pragma unroll
  for (int i = 0; i < 4; ++i) {
    #pragma unroll
    for (int j = 0; j < 2; ++j) {
      f32x4 a = acc[i][j];
      const int col = gn0 + j*16 + l16;
      const float bv = bias[col];
      const float c0v = cs[col];
      float c1v = 0.f, c2v = 0.f;
      if (!DO_GELU) { c1v = cs[256 + col]; c2v = cs[512 + col]; }
      #pragma unroll
      for (int r = 0; r < 4; ++r) {
        const int row = gm0 + i*16 + quad*4 + r;   // C/D: col=lane&15, row=quad*4+reg
        float v;
        if (DO_GELU) {
          v = istd*a[r] + mi*c0v + bv;
          v = 0.5f*v*(1.f + erff(v*0.70710678118654752f));
        } else {
          const int node = row >> 3;
          v = istd*a[r] + mi*(c0v + r1[node]*c1v + r2[node]*c2v) + bv;
        }
        float hv = (float)R[(size_t)row*ldr + col] + v;
        O[(size_t)row*ldo + col] = (_Float16)hv;
        s += hv; s2 += hv*hv;
      }
    }
  }
  red[t] = s; red[256+t] = s2; __syncthreads();
  for (int o = 128; o > 0; o >>= 1) {
    if (t < o) { red[t] += red[t+o]; red[256+t] += red[256+t+o]; }
    __syncthreads();
  }
  if (t == 0) part_out[blockIdx.y*gridDim.x + blockIdx.x] = make_float2(red[0], red[256]);
}

// ---- final mean over N: 256 blocks (b, 64-node chunk), one atomic per thread
//      into pre-zeroed out. 65K atomics / 2048 addresses = 32 per address. ----
__global__ __launch_bounds__(256) void k_mean(const _Float16* __restrict__ Acat,
                                              float* __restrict__ out) {
  int b = blockIdx.x & 7, chunk = blockIdx.x >> 3;   // 32 chunks x 64 nodes
  int c = threadIdx.x;
  float s = 0.f;
  for (int k = 0; k < 64; ++k) {
    int n = chunk*64 + k;
    s += (float)Acat[(size_t)(n*8 + b)*KCAT + c];
  }
  atomicAdd(&out[(b << 8) + c], s * (1.f/(float)NNODE));
}

extern "C" void kernel_launch(void* const* d_in, const int* in_sizes, int n_in,
                              void* d_out, int out_size, void* d_ws, size_t ws_size,
                              hipStream_t stream) {
  const float* x      = (const float*)d_in[0];   // node_feature [8,2048,256]
  const float* ew     = (const float*)d_in[1];   // edge_weight [3,32768]
  const float* cheb_w = (const float*)d_in[2];   // [3,3,256,256]
  const float* cheb_b = (const float*)d_in[3];   // [3,256]
  const float* mlp_w  = (const float*)d_in[4];   // [3,256,256]
  const float* mlp_b  = (const float*)d_in[5];   // [3,256]
  const int*   ei     = (const int*)d_in[6];     // [3,2,32768]
  float* out = (float*)d_out;

  char* ws = (char*)d_ws;
  _Float16*     Acat  = (_Float16*)(ws + OFF_ACAT);
  _Float16*     Hf    = (_Float16*)(ws + OFF_HF);
  _Float16*     Wt    = (_Float16*)(ws + OFF_WT);
  _Float16*     Mt    = (_Float16*)(ws + OFF_MT);
  float2*       partA = (float2*)(ws + OFF_PARTA);
  float2*       partB = (float2*)(ws + OFF_PARTB);
  float*        cs    = (float*)(ws + OFF_CS);
  float*        csM   = (float*)(ws + OFF_CSM);
  float*        deg   = (float*)(ws + OFF_DEG);
  unsigned int* cnt   = (unsigned int*)(ws + OFF_CNT);
  unsigned int* elist = (unsigned int*)(ws + OFF_ELIST);
  float*        r1    = (float*)(ws + OFF_R1);
  float*        r2    = (float*)(ws + OFF_R2);

  k_init<<<728, 256, 0, stream>>>(x, Acat, partA, cheb_w, mlp_w, Wt, Mt, deg, cnt);
  k_edge_scatter<<<397, 256, 0, stream>>>(ei, ew, deg, cnt, elist, Wt, Mt, cs, csM, out);

  for (int l = 0; l < NLAYER; ++l) {
    const int* rows_l = ei + l*2*NEDGE;
    const float* ew_l = ew + l*NEDGE;
    const float* deg_l = deg + l*NNODE;
    const unsigned int* cnt_l = cnt + l*NNODE;
    const unsigned int* el_l  = elist + (size_t)l*NNODE*64;
    float* r1_l = r1 + l*NNODE;
    float* r2_l = r2 + l*NNODE;

    // P1 = prop(h) -> Acat[:,256:512); bp==0 blocks also emit r1 = prop(ones)
    k_prop<0, 256, 1><<<2048, 256, 0, stream>>>(
        Acat, rows_l, ew_l, deg_l, cnt_l, el_l, r1_l, r2_l);
    // P2 = prop(P1) -> Acat[:,512:768); bp==0 blocks also emit r2 = prop(r1)
    k_prop<256, 512, 2><<<2048, 256, 0, stream>>>(
        Acat, rows_l, ew_l, deg_l, cnt_l, el_l, r1_l, r2_l);
    // Hf = h + LN-corrected [h|P1|P2]@W' + cheb_b ; stats -> partB
    k_gemm<6, 0><<<dim3(128, 4), 256, 0, stream>>>(
        Acat, KCAT, Wt + (size_t)l*CH*KCAT, KCAT, cheb_b + l*CH,
        cs + l*3*CH, r1_l, r2_l, partA, partB,
        Acat, KCAT, Hf, CH);
    // h(new, ->Acat0) = Hf + gelu(LN-corrected Hf@M + mlp_b) ; stats -> partA
    k_gemm<2, 1><<<dim3(128, 4), 256, 0, stream>>>(
        Hf, CH, Mt + (size_t)l*CH*CH, CH, mlp_b + l*CH,
        csM + l*CH, r1_l, r2_l, partB, partA,
        Hf, CH, Acat, KCAT);
  }

  k_mean<<<256, 256, 0, stream>>>(Acat, out);
}